// Round 3
// baseline (11.421 us; speedup 1.0000x reference)
//
#include <hip/hip_runtime.h>

// Closed-form Pauli contraction, v3: 3-way c8 DP split + branch-free halo loads.
//
// Frame (inherited, harness-verified): after folding layer-1 CNOTs into a
// GF(2) index remap, |psi> is a PRODUCT state over 9 physical bits (bit m
// holds qubit q = 8-m), and the conjugated observable is
//   O = prod_{p in {8,7,5,3,1}} h^(p),
//   h^(p) = al_p Z_{u_p} + br_p X_{w_p} + i bi_p Z_{u_p} X_{w_p}
// with u_p . w_q = delta_pq. Expanding into 3^5 = 243 Pauli terms Z_U X_W
// (trit c_p: 0->Z coeff al, 1->X coeff br, 2->ZX coeff i*bi), the
// product-state expectation factors per bit: <Z^u X^w> = 1 / z / x / i*y.
// Per-bit (U_m, W_m) staircase in the choice bits:
//   m=0:(a8,b1) m=1:(t1,b1) m=2:(t1,b3) m=3:(t3,b3) m=4:(t3,b5)
//   m=5:(t5,b5) m=6:(t5,b7) m=7:(t5^a7,b7^b8) m=8:(t5^a8^a7,b8)
//   t1=a8^a1, t3=t1^a3, t5=t3^a5  ->  4-level DP with state (t, c8).
//
// v3 vs v2 (9.40 us):
//  (1) 192-thread blocks: 3 waves own the same 64 samples; wave h evaluates
//      the c8 = h slice (81 terms each). Wave count 1024 -> 1536
//      (1.5 waves/SIMD), critical-wave DP drops from 2/3 to 1/3 of terms.
//  (2) Halo loads are branch-free: always load from a &63-wrapped (in-bounds)
//      address, then select 0 for out-of-range taps. All 9 VMEM ops issue
//      independently and retire under one vmcnt wait instead of a serialized
//      exec-mask branch chain.
// Purpose: discriminating experiment for the dur = O + k model
// (O ~ 8.3-8.9 us launch/graph floor, k ~ 1 us). If dur lands 9.0-9.2, the
// floor is confirmed and the session terminates at the dispatch-overhead limit.

#if defined(__clang__)
#pragma float_control(precise, off)   // fold the structural 0/1 components
#endif

struct C2 { float r, i; };
__device__ __forceinline__ C2 cmul(C2 a, C2 b) {
    return C2{a.r * b.r - a.i * b.i, a.r * b.i + a.i * b.r};
}
__device__ __forceinline__ C2 cadd(C2 a, C2 b) { return C2{a.r + b.r, a.i + b.i}; }

// DP over the c8-slice [C8BASE, C8BASE+NC8). Returns the partial expectation.
template<int C8BASE, int NC8>
__device__ __forceinline__ float dp_eval(const float (&Zb)[9], const float (&Xb)[9],
                                         const float (&Yb)[9], const float (&hm)[5][3]) {
    // per-bit complex Pauli factors F[m][U][W]; structural zeros fold at -O3
    C2 F[9][2][2];
    #pragma unroll
    for (int m = 0; m < 9; ++m) {
        F[m][0][0] = C2{1.0f, 0.0f};
        F[m][1][0] = C2{Zb[m], 0.0f};
        F[m][0][1] = C2{Xb[m], 0.0f};
        F[m][1][1] = C2{0.0f, Yb[m]};
    }
    // choice coefficients: slot 0=p8, 1=p7, 2=p5, 3=p3, 4=p1
    C2 K[5][3];
    #pragma unroll
    for (int i = 0; i < 5; ++i) {
        K[i][0] = C2{hm[i][0], 0.0f};   // alpha  (Z)
        K[i][1] = C2{hm[i][1], 0.0f};   // br     (X)
        K[i][2] = C2{0.0f, hm[i][2]};   // i*bi   (ZX)
    }
    const int A[3] = {1, 0, 1};
    const int B[3] = {0, 1, 1};

    // ---- level 7: bits 6,7,8 ----
    C2 S7[2][NC8];
    #pragma unroll
    for (int t5 = 0; t5 < 2; ++t5) {
        #pragma unroll
        for (int c8i = 0; c8i < NC8; ++c8i) {
            const int c8 = C8BASE + c8i;
            const int a8 = A[c8], b8 = B[c8];
            C2 acc = C2{0.0f, 0.0f};
            #pragma unroll
            for (int c7 = 0; c7 < 3; ++c7) {
                const int a7 = A[c7], b7 = B[c7];
                C2 v = cmul(K[1][c7], F[6][t5][b7]);
                v = cmul(v, F[7][t5 ^ a7][b7 ^ b8]);
                v = cmul(v, F[8][t5 ^ a8 ^ a7][b8]);
                acc = cadd(acc, v);
            }
            S7[t5][c8i] = acc;
        }
    }
    // ---- level 5: bits 4,5 ----
    C2 S5[2][NC8];
    #pragma unroll
    for (int t3 = 0; t3 < 2; ++t3) {
        #pragma unroll
        for (int c8i = 0; c8i < NC8; ++c8i) {
            C2 acc = C2{0.0f, 0.0f};
            #pragma unroll
            for (int c5 = 0; c5 < 3; ++c5) {
                const int a5 = A[c5], b5 = B[c5];
                C2 v = cmul(K[2][c5], F[4][t3][b5]);
                v = cmul(v, F[5][t3 ^ a5][b5]);
                v = cmul(v, S7[t3 ^ a5][c8i]);
                acc = cadd(acc, v);
            }
            S5[t3][c8i] = acc;
        }
    }
    // ---- level 3: bits 2,3 ----
    C2 S3[2][NC8];
    #pragma unroll
    for (int t1 = 0; t1 < 2; ++t1) {
        #pragma unroll
        for (int c8i = 0; c8i < NC8; ++c8i) {
            C2 acc = C2{0.0f, 0.0f};
            #pragma unroll
            for (int c3 = 0; c3 < 3; ++c3) {
                const int a3 = A[c3], b3 = B[c3];
                C2 v = cmul(K[3][c3], F[2][t1][b3]);
                v = cmul(v, F[3][t1 ^ a3][b3]);
                v = cmul(v, S5[t1 ^ a3][c8i]);
                acc = cadd(acc, v);
            }
            S3[t1][c8i] = acc;
        }
    }
    // ---- level 1: bits 0,1, then close over c8 (every term is real) ----
    float E = 0.0f;
    #pragma unroll
    for (int c8i = 0; c8i < NC8; ++c8i) {
        const int c8 = C8BASE + c8i;
        const int a8 = A[c8];
        C2 acc = C2{0.0f, 0.0f};
        #pragma unroll
        for (int c1 = 0; c1 < 3; ++c1) {
            const int a1 = A[c1], b1 = B[c1];
            C2 v = cmul(K[4][c1], F[0][a8][b1]);
            v = cmul(v, F[1][a8 ^ a1][b1]);
            v = cmul(v, S3[a8 ^ a1][c8i]);
            acc = cadd(acc, v);
        }
        E += K[0][c8].r * acc.r - K[0][c8].i * acc.i;
    }
    return E;
}

__global__ __launch_bounds__(192) void qsim_kernel(const float* __restrict__ x,
                                                   const float* __restrict__ w,
                                                   float* __restrict__ out,
                                                   int nsamples) {
    __shared__ float cb[9][6];    // per qubit: {Cz_z, Cy_z, Cz_x, Cy_x, Cz_y, Cy_y}
    __shared__ float hm[5][3];    // h params for p = 8,7,5,3,1: {alpha, beta_r, beta_i}
    __shared__ float part[2][64]; // wave-1/2 partials
    const int tid = threadIdx.x;
    if (tid < 9) {
        const int q = tid;
        const float phi = w[q * 3 + 0], theta = w[q * 3 + 1], omega = w[q * 3 + 2];
        float st, ct, sp, cp, sm, cm;
        __sincosf(0.5f * theta, &st, &ct);
        __sincosf(0.5f * (phi + omega), &sp, &cp);
        __sincosf(0.5f * (phi - omega), &sm, &cm);
        const float m00r =  cp * ct, m00i = -sp * ct;
        const float m01r = -cm * st, m01i = -sm * st;
        const float m10r =  cm * st, m10i = -sm * st;
        const float m11r =  cp * ct, m11i =  sp * ct;
        // Cz = Bloch(U|0>) = Bloch((m00, m10)), components (z, x, y)
        cb[q][0] = (m00r * m00r + m00i * m00i) - (m10r * m10r + m10i * m10i);
        cb[q][2] = 2.0f * (m00r * m10r + m00i * m10i);
        cb[q][4] = 2.0f * (m00r * m10i - m00i * m10r);
        // Cy = Bloch(U|y+>), |y+> = (|0>+i|1>)/sqrt2 -> u = (m00+i*m01, m10+i*m11)/sqrt2
        const float u0r = m00r - m01i, u0i = m00i + m01r;
        const float u1r = m10r - m11i, u1i = m10i + m11r;
        cb[q][1] = 0.5f * ((u0r * u0r + u0i * u0i) - (u1r * u1r + u1i * u1i));
        cb[q][3] = (u0r * u1r + u0i * u1i);
        cb[q][5] = (u0r * u1i - u0i * u1r);
    } else if (tid >= 16 && tid < 21) {
        const int i = tid - 16;
        const int qs[5] = {0, 1, 3, 5, 7};  // wire q; logical p = 8,7,5,3,1
        const int q = qs[i];
        const float phi = w[27 + q * 3 + 0], theta = w[27 + q * 3 + 1];
        float stt, ctt, sf, cf;
        __sincosf(theta, &stt, &ctt);
        __sincosf(phi, &sf, &cf);
        hm[i][0] = ctt;          // alpha = cos(theta)
        hm[i][1] = -stt * cf;    // beta  = -sin(theta) e^{i phi}
        hm[i][2] = -stt * sf;
    }
    __syncthreads();

    const int lane = tid & 63;
    const int wv = tid >> 6;                 // wave id 0..2 (uniform per wave)
    const int n = (blockIdx.x << 6) + lane;  // all 3 waves own the same 64 samples

    float E = 0.0f;
    if (n < nsamples) {
        const int b  = n >> 12;
        const int i0 = (n >> 6) & 63;
        const int j0 = n & 63;               // lane == column -> coalesced loads

        // Bloch components per physical bit m (qubit q = 8 - m):
        // Bloch(U_q RX(a)|0>) = cos(a) * Cz_q - sin(a) * Cy_q
        float Zb[9], Xb[9], Yb[9];
        #pragma unroll
        for (int ki = 0; ki < 3; ++ki) {
            #pragma unroll
            for (int kj = 0; kj < 3; ++kj) {
                const int q = ki * 3 + kj;
                const int m = 8 - q;
                const int ii = i0 + ki - 1, jj = j0 + kj - 1;
                // branch-free: wrapped address is always in-bounds; mask after
                const bool ok = ((unsigned)ii < 64u) & ((unsigned)jj < 64u);
                float a = x[(b << 12) + ((ii & 63) << 6) + (jj & 63)];
                a = ok ? a : 0.0f;
                float sa, ca;
                __sincosf(a, &sa, &ca);
                Zb[m] = ca * cb[q][0] - sa * cb[q][1];
                Xb[m] = ca * cb[q][2] - sa * cb[q][3];
                Yb[m] = ca * cb[q][4] - sa * cb[q][5];
            }
        }
        if      (wv == 0) E = dp_eval<0, 1>(Zb, Xb, Yb, hm);  // c8 = 0
        else if (wv == 1) E = dp_eval<1, 1>(Zb, Xb, Yb, hm);  // c8 = 1
        else              E = dp_eval<2, 1>(Zb, Xb, Yb, hm);  // c8 = 2
    }
    if (wv) part[wv - 1][lane] = E;
    __syncthreads();
    if (wv == 0 && n < nsamples) out[n] = E + part[0][lane] + part[1][lane];
}

extern "C" void kernel_launch(void* const* d_in, const int* in_sizes, int n_in,
                              void* d_out, int out_size, void* d_ws, size_t ws_size,
                              hipStream_t stream) {
    const float* x = (const float*)d_in[0];   // (8,1,64,64) float32
    const float* w = (const float*)d_in[1];   // (2,9,3) float32
    float* out = (float*)d_out;               // 32768 float32
    const int nsamples = out_size;
    const int blocks = (nsamples + 63) >> 6;  // 64 samples per 192-thread block
    qsim_kernel<<<blocks, 192, 0, stream>>>(x, w, out, nsamples);
}